// Round 4
// baseline (130.288 us; speedup 1.0000x reference)
//
#include <hip/hip_runtime.h>
#include <math.h>

// Problem constants (N=64, C=256, H=56, W=56, K=8)
#define NB   64
#define CB   256
#define KB   8
#define HWSZ 3136          // 56*56
#define HW4  784           // HWSZ/4 (float4 per plane)
#define PLANES (NB*CB)     // 16384
#define EPSV 1e-5f

typedef float    floatx4 __attribute__((ext_vector_type(4)));
typedef _Float16 halfx4  __attribute__((ext_vector_type(4)));

// ---------------------------------------------------------------------------
// Kernel 1: per-(n,c) spatial mean / mean-of-squares + fp16 shadow of x.
// nt-loads for x: the streaming read must NOT allocate in L3 (it would evict
// the shadow). Shadow stores are regular (write-allocate -> L3-resident).
// ---------------------------------------------------------------------------
__global__ __launch_bounds__(256) void k_stats(const float* __restrict__ x,
                                               _Float16* __restrict__ xh,
                                               float* __restrict__ xm,
                                               float* __restrict__ x2m,
                                               int do_shadow) {
    const int plane = blockIdx.x;
    const floatx4* xp = (const floatx4*)(x + (size_t)plane * HWSZ);
    halfx4* hp = (halfx4*)(xh + (size_t)plane * HWSZ);

    float s = 0.f, s2 = 0.f;
    for (int i = threadIdx.x; i < HW4; i += 256) {
        floatx4 v = __builtin_nontemporal_load(&xp[i]);
        s  += v.x + v.y + v.z + v.w;
        s2 += v.x*v.x + v.y*v.y + v.z*v.z + v.w*v.w;
        if (do_shadow) {
            halfx4 h;
            h.x = (_Float16)v.x; h.y = (_Float16)v.y;
            h.z = (_Float16)v.z; h.w = (_Float16)v.w;
            hp[i] = h;
        }
    }
    #pragma unroll
    for (int off = 32; off > 0; off >>= 1) {
        s  += __shfl_down(s,  off, 64);
        s2 += __shfl_down(s2, off, 64);
    }
    __shared__ float ls[4], ls2[4];
    const int lane = threadIdx.x & 63;
    const int w    = threadIdx.x >> 6;
    if (lane == 0) { ls[w] = s; ls2[w] = s2; }
    __syncthreads();
    if (threadIdx.x == 0) {
        float t  = ls[0]  + ls[1]  + ls[2]  + ls[3];
        float t2 = ls2[0] + ls2[1] + ls2[2] + ls2[3];
        xm[plane]  = t  * (1.f / HWSZ);
        x2m[plane] = t2 * (1.f / HWSZ);
    }
}

// ---------------------------------------------------------------------------
// Kernel 2: 8 blocks (one per expert). Each block redundantly computes the
// full gate matrix (logits + softmax, tiny), then its expert's weighted
// mean/rstd per channel. Block 0 also publishes g.
// ---------------------------------------------------------------------------
__global__ __launch_bounds__(256) void k_gate8(const float* __restrict__ xm,
                                               const float* __restrict__ x2m,
                                               const float* __restrict__ Ww,
                                               const float* __restrict__ Wb,
                                               float* __restrict__ g,        // [N*K]
                                               float* __restrict__ rstd,     // [K*C]
                                               float* __restrict__ murstd) { // [K*C]
    __shared__ float lg[NB][KB];
    __shared__ float gs[NB][KB];
    const int tid = threadIdx.x;

    // logits (512 dot products of length 256, 2 per thread)
    for (int p = tid; p < NB * KB; p += 256) {
        const int n = p >> 3, k = p & 7;
        const float* xr = xm + n * CB;
        const float* wr = Ww + k * CB;
        float acc = 0.f;
        #pragma unroll 8
        for (int c = 0; c < CB; ++c) acc = fmaf(xr[c], wr[c], acc);
        lg[n][k] = acc + Wb[k];
    }
    __syncthreads();

    // softmax per row (threads 0..63)
    if (tid < NB) {
        float m = lg[tid][0];
        #pragma unroll
        for (int j = 1; j < KB; ++j) m = fmaxf(m, lg[tid][j]);
        float e[KB], s = 0.f;
        #pragma unroll
        for (int j = 0; j < KB; ++j) { e[j] = expf(lg[tid][j] - m); s += e[j]; }
        const float inv = 1.f / s;
        #pragma unroll
        for (int j = 0; j < KB; ++j) gs[tid][j] = e[j] * inv;
    }
    __syncthreads();

    // expert stats for k = blockIdx.x, one thread per channel
    const int k = blockIdx.x;
    const int c = tid;
    float sg = 0.f, sm = 0.f, s2 = 0.f;
    #pragma unroll 8
    for (int n = 0; n < NB; ++n) {
        const float gn = gs[n][k];             // LDS broadcast
        sg += gn;
        sm = fmaf(gn, xm[n * CB + c], sm);
        s2 = fmaf(gn, x2m[n * CB + c], s2);
    }
    const float inv = 1.f / sg;
    const float mu  = sm * inv;
    const float var = fmaf(-mu, mu, s2 * inv);
    const float rs  = rsqrtf(var + EPSV);
    rstd[k * CB + c]   = rs;
    murstd[k * CB + c] = mu * rs;

    if (blockIdx.x == 0) {
        for (int p = tid; p < NB * KB; p += 256) g[p] = gs[p >> 3][p & 7];
    }
}

// ---------------------------------------------------------------------------
// Kernel 3a: apply from fp16 shadow (L3-resident): out = xh*sc + sh.
// halfx4 loads (8 B/lane), float4 nt-stores (16 B/lane, contiguous).
// ---------------------------------------------------------------------------
__global__ __launch_bounds__(256) void k_apply_h(const _Float16* __restrict__ xh,
                                                 const float* __restrict__ g,
                                                 const float* __restrict__ rstd,
                                                 const float* __restrict__ murstd,
                                                 const float* __restrict__ alpha,
                                                 const float* __restrict__ beta,
                                                 float* __restrict__ out) {
    const int plane = blockIdx.x;
    const int n = plane >> 8, c = plane & 255;

    float a = 0.f, b = 0.f;
    #pragma unroll
    for (int k = 0; k < KB; ++k) {
        const float gk = g[n * KB + k];        // uniform -> scalar loads
        a = fmaf(gk, rstd[k * CB + c],   a);
        b = fmaf(gk, murstd[k * CB + c], b);
    }
    const float al = alpha[c];
    const float sc = al * a;
    const float sh = fmaf(-al, b, beta[c]);

    const halfx4* hp = (const halfx4*)(xh + (size_t)plane * HWSZ);
    floatx4* op = (floatx4*)(out + (size_t)plane * HWSZ);
    for (int i = threadIdx.x; i < HW4; i += 256) {
        halfx4 h = hp[i];
        floatx4 r;
        r.x = fmaf((float)h.x, sc, sh);
        r.y = fmaf((float)h.y, sc, sh);
        r.z = fmaf((float)h.z, sc, sh);
        r.w = fmaf((float)h.w, sc, sh);
        __builtin_nontemporal_store(r, &op[i]);
    }
}

// ---------------------------------------------------------------------------
// Kernel 3b: fallback — apply straight from x (if ws can't hold the shadow).
// ---------------------------------------------------------------------------
__global__ __launch_bounds__(256) void k_apply_f(const float* __restrict__ x,
                                                 const float* __restrict__ g,
                                                 const float* __restrict__ rstd,
                                                 const float* __restrict__ murstd,
                                                 const float* __restrict__ alpha,
                                                 const float* __restrict__ beta,
                                                 float* __restrict__ out) {
    const int plane = blockIdx.x;
    const int n = plane >> 8, c = plane & 255;

    float a = 0.f, b = 0.f;
    #pragma unroll
    for (int k = 0; k < KB; ++k) {
        const float gk = g[n * KB + k];
        a = fmaf(gk, rstd[k * CB + c],   a);
        b = fmaf(gk, murstd[k * CB + c], b);
    }
    const float al = alpha[c];
    const float sc = al * a;
    const float sh = fmaf(-al, b, beta[c]);

    const floatx4* xp = (const floatx4*)(x + (size_t)plane * HWSZ);
    floatx4* op = (floatx4*)(out + (size_t)plane * HWSZ);
    for (int i = threadIdx.x; i < HW4; i += 256) {
        floatx4 v = xp[i];
        floatx4 r;
        r.x = fmaf(v.x, sc, sh);
        r.y = fmaf(v.y, sc, sh);
        r.z = fmaf(v.z, sc, sh);
        r.w = fmaf(v.w, sc, sh);
        __builtin_nontemporal_store(r, &op[i]);
    }
}

extern "C" void kernel_launch(void* const* d_in, const int* in_sizes, int n_in,
                              void* d_out, int out_size, void* d_ws, size_t ws_size,
                              hipStream_t stream) {
    const float* x     = (const float*)d_in[0];
    const float* Ww    = (const float*)d_in[1];
    const float* Wb    = (const float*)d_in[2];
    const float* alpha = (const float*)d_in[3];
    const float* beta  = (const float*)d_in[4];
    float* out = (float*)d_out;

    // ws layout: [xh: PLANES*HWSZ halves][xm][x2m][g][rstd][murstd]
    const size_t shadow_elems = (size_t)PLANES * HWSZ;          // 51.4M halves
    const size_t small_floats = 2 * PLANES + NB * KB + 2 * KB * CB;
    const size_t need = shadow_elems * sizeof(_Float16) + small_floats * sizeof(float);
    const int use_shadow = (ws_size >= need) ? 1 : 0;

    _Float16* xh = (_Float16*)d_ws;
    float* smallp = use_shadow ? (float*)(xh + shadow_elems) : (float*)d_ws;
    float* xm     = smallp;
    float* x2m    = xm + PLANES;
    float* g      = x2m + PLANES;
    float* rstd   = g + NB * KB;
    float* murstd = rstd + KB * CB;

    k_stats <<<PLANES, 256, 0, stream>>>(x, xh, xm, x2m, use_shadow);
    k_gate8 <<<KB,     256, 0, stream>>>(xm, x2m, Ww, Wb, g, rstd, murstd);
    if (use_shadow)
        k_apply_h<<<PLANES, 256, 0, stream>>>(xh, g, rstd, murstd, alpha, beta, out);
    else
        k_apply_f<<<PLANES, 256, 0, stream>>>(x, g, rstd, murstd, alpha, beta, out);
}

// Round 5
// 119.684 us; speedup vs baseline: 1.0886x; 1.0886x over previous
//
#include <hip/hip_runtime.h>
#include <math.h>

// Problem constants (N=64, C=256, H=56, W=56, K=8)
#define NB   64
#define CB   256
#define KB   8
#define HWSZ 3136          // 56*56
#define HW4  784           // HWSZ/4 (float4 per plane)
#define PLANES (NB*CB)     // 16384
#define EPSV 1e-5f

typedef float floatx4 __attribute__((ext_vector_type(4)));

// ---------------------------------------------------------------------------
// Kernel 1: per-(n,c) spatial mean and mean-of-squares.
// One 256-thread block per plane, planes touched in ascending order.
// Regular (caching) loads on purpose: leaves x L3-resident with LRU age =
// plane order, which k_apply exploits by walking planes in reverse.
// ---------------------------------------------------------------------------
__global__ __launch_bounds__(256) void k_stats(const float* __restrict__ x,
                                               float* __restrict__ xm,
                                               float* __restrict__ x2m) {
    const int plane = blockIdx.x;
    const floatx4* xp = (const floatx4*)(x + (size_t)plane * HWSZ);

    float s = 0.f, s2 = 0.f;
    for (int i = threadIdx.x; i < HW4; i += 256) {
        floatx4 v = xp[i];
        s  += v.x + v.y + v.z + v.w;
        s2 += v.x*v.x + v.y*v.y + v.z*v.z + v.w*v.w;
    }
    #pragma unroll
    for (int off = 32; off > 0; off >>= 1) {
        s  += __shfl_down(s,  off, 64);
        s2 += __shfl_down(s2, off, 64);
    }
    __shared__ float ls[4], ls2[4];
    const int lane = threadIdx.x & 63;
    const int w    = threadIdx.x >> 6;
    if (lane == 0) { ls[w] = s; ls2[w] = s2; }
    __syncthreads();
    if (threadIdx.x == 0) {
        float t  = ls[0]  + ls[1]  + ls[2]  + ls[3];
        float t2 = ls2[0] + ls2[1] + ls2[2] + ls2[3];
        xm[plane]  = t  * (1.f / HWSZ);
        x2m[plane] = t2 * (1.f / HWSZ);
    }
}

// ---------------------------------------------------------------------------
// Kernel 2: 8 blocks (one per expert). Each block redundantly computes the
// full gate matrix (logits + softmax, tiny), then its expert's weighted
// mean/rstd per channel. Block 0 also publishes g.
// ---------------------------------------------------------------------------
__global__ __launch_bounds__(256) void k_gate8(const float* __restrict__ xm,
                                               const float* __restrict__ x2m,
                                               const float* __restrict__ Ww,
                                               const float* __restrict__ Wb,
                                               float* __restrict__ g,        // [N*K]
                                               float* __restrict__ rstd,     // [K*C]
                                               float* __restrict__ murstd) { // [K*C]
    __shared__ float lg[NB][KB];
    __shared__ float gs[NB][KB];
    const int tid = threadIdx.x;

    // logits (512 dot products of length 256, 2 per thread)
    for (int p = tid; p < NB * KB; p += 256) {
        const int n = p >> 3, k = p & 7;
        const float* xr = xm + n * CB;
        const float* wr = Ww + k * CB;
        float acc = 0.f;
        #pragma unroll 8
        for (int c = 0; c < CB; ++c) acc = fmaf(xr[c], wr[c], acc);
        lg[n][k] = acc + Wb[k];
    }
    __syncthreads();

    // softmax per row (threads 0..63)
    if (tid < NB) {
        float m = lg[tid][0];
        #pragma unroll
        for (int j = 1; j < KB; ++j) m = fmaxf(m, lg[tid][j]);
        float e[KB], s = 0.f;
        #pragma unroll
        for (int j = 0; j < KB; ++j) { e[j] = expf(lg[tid][j] - m); s += e[j]; }
        const float inv = 1.f / s;
        #pragma unroll
        for (int j = 0; j < KB; ++j) gs[tid][j] = e[j] * inv;
    }
    __syncthreads();

    // expert stats for k = blockIdx.x, one thread per channel
    const int k = blockIdx.x;
    const int c = tid;
    float sg = 0.f, sm = 0.f, s2 = 0.f;
    #pragma unroll 8
    for (int n = 0; n < NB; ++n) {
        const float gn = gs[n][k];             // LDS broadcast
        sg += gn;
        sm = fmaf(gn, xm[n * CB + c], sm);
        s2 = fmaf(gn, x2m[n * CB + c], s2);
    }
    const float inv = 1.f / sg;
    const float mu  = sm * inv;
    const float var = fmaf(-mu, mu, s2 * inv);
    const float rs  = rsqrtf(var + EPSV);
    rstd[k * CB + c]   = rs;
    murstd[k * CB + c] = mu * rs;

    if (blockIdx.x == 0) {
        for (int p = tid; p < NB * KB; p += 256) g[p] = gs[p >> 3][p & 7];
    }
}

// ---------------------------------------------------------------------------
// Kernel 3: out = x * scale + shift. Planes walked in REVERSE order so the
// L3-resident tail of x (MRU after k_stats) is consumed before out-write
// eviction pressure (which targets LRU = low planes) reaches it.
// Non-temporal stores for out to minimize allocation where honored.
// ---------------------------------------------------------------------------
__global__ __launch_bounds__(256) void k_apply(const float* __restrict__ x,
                                               const float* __restrict__ g,
                                               const float* __restrict__ rstd,
                                               const float* __restrict__ murstd,
                                               const float* __restrict__ alpha,
                                               const float* __restrict__ beta,
                                               float* __restrict__ out) {
    const int plane = (PLANES - 1) - blockIdx.x;   // reverse walk
    const int n = plane >> 8, c = plane & 255;

    float a = 0.f, b = 0.f;
    #pragma unroll
    for (int k = 0; k < KB; ++k) {
        const float gk = g[n * KB + k];        // uniform -> scalar loads
        a = fmaf(gk, rstd[k * CB + c],   a);
        b = fmaf(gk, murstd[k * CB + c], b);
    }
    const float al = alpha[c];
    const float sc = al * a;
    const float sh = fmaf(-al, b, beta[c]);

    const floatx4* xp = (const floatx4*)(x + (size_t)plane * HWSZ);
    floatx4* op = (floatx4*)(out + (size_t)plane * HWSZ);
    for (int i = threadIdx.x; i < HW4; i += 256) {
        floatx4 v = xp[i];
        floatx4 r;
        r.x = fmaf(v.x, sc, sh);
        r.y = fmaf(v.y, sc, sh);
        r.z = fmaf(v.z, sc, sh);
        r.w = fmaf(v.w, sc, sh);
        __builtin_nontemporal_store(r, &op[i]);
    }
}

extern "C" void kernel_launch(void* const* d_in, const int* in_sizes, int n_in,
                              void* d_out, int out_size, void* d_ws, size_t ws_size,
                              hipStream_t stream) {
    const float* x     = (const float*)d_in[0];
    const float* Ww    = (const float*)d_in[1];
    const float* Wb    = (const float*)d_in[2];
    const float* alpha = (const float*)d_in[3];
    const float* beta  = (const float*)d_in[4];
    float* out = (float*)d_out;

    float* ws     = (float*)d_ws;
    float* xm     = ws;                      // [N*C]
    float* x2m    = ws + PLANES;             // [N*C]
    float* g      = ws + 2 * PLANES;         // [N*K]
    float* rstd   = g + NB * KB;             // [K*C]
    float* murstd = rstd + KB * CB;          // [K*C]

    k_stats <<<PLANES, 256, 0, stream>>>(x, xm, x2m);
    k_gate8 <<<KB,     256, 0, stream>>>(xm, x2m, Ww, Wb, g, rstd, murstd);
    k_apply <<<PLANES, 256, 0, stream>>>(x, g, rstd, murstd, alpha, beta, out);
}